// Round 1
// baseline (248.587 us; speedup 1.0000x reference)
//
#include <hip/hip_runtime.h>

// Edge MLP: score = relu((h[src]*h[dst]) @ W1 + b1) @ W2 + b2
// N_NODES=50000, N_EDGES=600000, D_IN=128, D_HID=64, OUT=2
//
// Mapping: lane = edge. Each wave owns 64 edges. The wave cooperatively
// stages e[edge][k] = h[src][k]*h[dst][k] into LDS (coalesced row loads,
// stride-65 padding -> conflict-free), then each lane runs the MLP for its
// own edge: per k one ds_read_b32 (own e[k]) + 64 FMAs with W1 from
// wave-uniform s_loads (SGPR operand, free). ds:FMA = 1:64 -> FMA-bound.

#define NEDGE 600000
#define DIN 128
#define DH 64

__global__ __launch_bounds__(128, 2) void mlp_edge_kernel(
    const float* __restrict__ h,
    const float* __restrict__ W1,
    const float* __restrict__ b1,
    const float* __restrict__ W2,
    const float* __restrict__ b2,
    const int* __restrict__ src,
    const int* __restrict__ dst,
    float* __restrict__ out)
{
    // per-wave e-buffer: 64 edges x 65-float stride (pad -> bank = (edge+k)%32)
    __shared__ float e_lds[2 * 64 * 65];

    const int wave = threadIdx.x >> 6;
    const int l = threadIdx.x & 63;
    const long long wbase = (long long)blockIdx.x * 128 + wave * 64;
    int nv = (int)(NEDGE - wbase);
    if (nv > 64) nv = 64;
    if (nv < 0) nv = 0;

    int my_s = 0, my_d = 0;
    if (l < nv) {
        my_s = src[wbase + l];
        my_d = dst[wbase + l];
    }

    float acc[DH];
#pragma unroll
    for (int j = 0; j < DH; ++j) acc[j] = b1[j];

    float* elds = &e_lds[wave * (64 * 65)];

#pragma unroll
    for (int p = 0; p < 2; ++p) {
        const int kb = p * 64;

        // ---- stage e[i][kb + l] for the wave's 64 edges ----
        if (nv == 64) {
#pragma unroll 8
            for (int i = 0; i < 64; ++i) {
                int si = __builtin_amdgcn_readlane(my_s, i);
                int di = __builtin_amdgcn_readlane(my_d, i);
                float a = h[(size_t)si * DIN + kb + l];
                float b = h[(size_t)di * DIN + kb + l];
                elds[i * 65 + l] = a * b;
            }
        } else {
            for (int i = 0; i < nv; ++i) {
                int si = __builtin_amdgcn_readlane(my_s, i);
                int di = __builtin_amdgcn_readlane(my_d, i);
                float a = h[(size_t)si * DIN + kb + l];
                float b = h[(size_t)di * DIN + kb + l];
                elds[i * 65 + l] = a * b;
            }
        }
        // same-wave DS ordering guarantees write->read consistency (per-wave
        // in-order LDS pipe); no __syncthreads needed (regions are per-wave).

        // ---- accumulate hid over this k-phase ----
#pragma unroll 2
        for (int k = 0; k < 64; ++k) {
            float ev = elds[l * 65 + k];
            const float* wrow = W1 + (size_t)(kb + k) * DH;  // wave-uniform -> s_load
#pragma unroll
            for (int j = 0; j < DH; ++j) acc[j] = fmaf(wrow[j], ev, acc[j]);
        }
    }

    // ---- layer 2: relu + [64]->[2], W2/b2 wave-uniform ----
    float s0 = b2[0], s1 = b2[1];
#pragma unroll
    for (int j = 0; j < DH; ++j) {
        float v = fmaxf(acc[j], 0.0f);
        s0 = fmaf(v, W2[j * 2 + 0], s0);
        s1 = fmaf(v, W2[j * 2 + 1], s1);
    }

    if (l < nv) {
        float2 o = make_float2(s0, s1);
        *reinterpret_cast<float2*>(out + (size_t)(wbase + l) * 2) = o;
    }
}

extern "C" void kernel_launch(void* const* d_in, const int* in_sizes, int n_in,
                              void* d_out, int out_size, void* d_ws, size_t ws_size,
                              hipStream_t stream) {
    const float* h  = (const float*)d_in[0];
    const float* W1 = (const float*)d_in[1];
    const float* b1 = (const float*)d_in[2];
    const float* W2 = (const float*)d_in[3];
    const float* b2 = (const float*)d_in[4];
    const int* src  = (const int*)d_in[5];
    const int* dst  = (const int*)d_in[6];
    float* out = (float*)d_out;

    int blocks = (NEDGE + 127) / 128;
    mlp_edge_kernel<<<blocks, 128, 0, stream>>>(h, W1, b1, W2, b2, src, dst, out);
}

// Round 2
// 100.137 us; speedup vs baseline: 2.4825x; 2.4825x over previous
//
#include <hip/hip_runtime.h>
#include <hip/hip_bf16.h>

// Edge MLP via MFMA: score = relu((h[src]*h[dst]) @ W1 + b1) @ W2 + b2
// N_EDGES=600000, D_IN=128, D_HID=64, OUT=2. 600000 % 64 == 0 -> every
// wave owns exactly 64 edges (last block has 1 dummy wave, clamped loads,
// guarded stores, NO early return so the barrier stays safe).
//
// Per wave: C[64 edges][64 hid] = e[64][128] @ W1[128][64] via
// mfma_f32_16x16x32_bf16, 4 m-tiles x 4 n-tiles x 4 k-steps = 64 MFMA.
// A-frags built in registers from gathered fp32 h rows (lane l handles
// edge m*16+(l&15), k-slice (l>>4)*8..+7; the 4 g-lanes of a row together
// read one contiguous 128B chunk -> line-granular gather). B-frags read
// from per-block LDS W1^T (bf16, 16B-aligned b128 reads). Any consistent
// k-permutation between A and B frags is correctness-neutral; only the
// C/D layout (col=lane&15, row=(lane>>4)*4+reg, HW-verified) matters.

#define NEDGE 600000
#define DIN 128
#define DH 64
#define STRK 136  // W1t row stride in shorts (128 + 8 pad); 272B = 16*17 keeps 16B align

typedef __attribute__((ext_vector_type(8))) short bf16x8;
typedef __attribute__((ext_vector_type(4))) float f32x4;

static __device__ __forceinline__ short f2bf(float f) {
    __hip_bfloat16 hb = __float2bfloat16(f);
    return *reinterpret_cast<short*>(&hb);
}

__global__ __launch_bounds__(256) void mlp_edge_mfma(
    const float* __restrict__ h,
    const float* __restrict__ W1,
    const float* __restrict__ b1,
    const float* __restrict__ W2,
    const float* __restrict__ b2,
    const int* __restrict__ src,
    const int* __restrict__ dst,
    float* __restrict__ out)
{
    __shared__ unsigned short w1t[DH * STRK];  // [col][k] bf16, transposed W1

    const int tid = threadIdx.x;

    // ---- build W1^T (bf16) cooperatively: 8192 floats / 256 thr = 8 float4 each
#pragma unroll
    for (int j = 0; j < 8; ++j) {
        int flat = (tid + j * 256) * 4;                 // multiple of 4 -> same k row
        f32x4 w = *reinterpret_cast<const f32x4*>(W1 + flat);
        int k = flat >> 6;   // /DH
        int c = flat & 63;
#pragma unroll
        for (int q = 0; q < 4; ++q)
            w1t[(c + q) * STRK + k] = (unsigned short)f2bf(w[q]);
    }
    __syncthreads();

    const int wave = tid >> 6;
    const int l = tid & 63;
    const int lr = l & 15;   // M-row / N-col within 16
    const int g = l >> 4;    // k-group (8 elems each)
    const long long wbase = ((long long)blockIdx.x * 4 + wave) * 64;

    // per-lane gather bases for the 4 m-tiles (byte offsets into h)
    unsigned int sa[4], da[4];
#pragma unroll
    for (int m = 0; m < 4; ++m) {
        long long e = wbase + m * 16 + lr;
        if (e >= NEDGE) e = NEDGE - 1;                  // clamp (dummy wave / none)
        sa[m] = (unsigned int)src[e] * (DIN * 4u);
        da[m] = (unsigned int)dst[e] * (DIN * 4u);
    }

    // acc init with b1 (broadcast over rows)
    f32x4 acc[4][4];
#pragma unroll
    for (int n = 0; n < 4; ++n) {
        float bv = b1[n * 16 + lr];
#pragma unroll
        for (int m = 0; m < 4; ++m) acc[m][n] = (f32x4){bv, bv, bv, bv};
    }

    const char* hb8 = (const char*)h;

#pragma unroll
    for (int ks = 0; ks < 4; ++ks) {
        // B-frags: W1t[col = n*16+lr][k = ks*32 + g*8 .. +7] -> one b128 each
        bf16x8 B[4];
#pragma unroll
        for (int n = 0; n < 4; ++n) {
            const unsigned short* p = &w1t[(n * 16 + lr) * STRK + ks * 32 + g * 8];
            B[n] = *reinterpret_cast<const bf16x8*>(p);
        }
#pragma unroll
        for (int m = 0; m < 4; ++m) {
            const unsigned int off = (unsigned)(ks * 128 + g * 32);
            f32x4 s0 = *reinterpret_cast<const f32x4*>(hb8 + sa[m] + off);
            f32x4 s1 = *reinterpret_cast<const f32x4*>(hb8 + sa[m] + off + 16);
            f32x4 d0 = *reinterpret_cast<const f32x4*>(hb8 + da[m] + off);
            f32x4 d1 = *reinterpret_cast<const f32x4*>(hb8 + da[m] + off + 16);
            bf16x8 A;
#pragma unroll
            for (int q = 0; q < 4; ++q) {
                A[q]     = f2bf(s0[q] * d0[q]);
                A[q + 4] = f2bf(s1[q] * d1[q]);
            }
#pragma unroll
            for (int n = 0; n < 4; ++n)
                acc[m][n] = __builtin_amdgcn_mfma_f32_16x16x32_bf16(A, B[n], acc[m][n], 0, 0, 0);
        }
    }

    // ---- layer 2: relu + [64]->[2] with 16-lane butterfly reduction ----
    float w2v[4][2];
#pragma unroll
    for (int n = 0; n < 4; ++n) {
        float2 w = *reinterpret_cast<const float2*>(W2 + (n * 16 + lr) * 2);
        w2v[n][0] = w.x; w2v[n][1] = w.y;
    }
    const float bb0 = b2[0], bb1 = b2[1];

    float o0 = 0.f, o1 = 0.f;
#pragma unroll
    for (int m = 0; m < 4; ++m) {
#pragma unroll
        for (int r = 0; r < 4; ++r) {
            float p0 = 0.f, p1 = 0.f;
#pragma unroll
            for (int n = 0; n < 4; ++n) {
                float v = fmaxf(acc[m][n][r], 0.f);
                p0 = fmaf(v, w2v[n][0], p0);
                p1 = fmaf(v, w2v[n][1], p1);
            }
            // sum over the 16 lanes of this g-group (lane bits 0..3)
#pragma unroll
            for (int sh = 1; sh < 16; sh <<= 1) {
                p0 += __shfl_xor(p0, sh, 64);
                p1 += __shfl_xor(p1, sh, 64);
            }
            if (lr == m * 4 + r) { o0 = p0; o1 = p1; }   // this lane writes edge (m, g, r)
        }
    }
    // lane l writes edge = wbase + m*16 + g*4 + r with m = lr>>2, r = lr&3
    long long edge = wbase + ((long long)(lr >> 2) * 16) + g * 4 + (lr & 3);
    if (edge < NEDGE) {
        float2 ov = make_float2(o0 + bb0, o1 + bb1);
        *reinterpret_cast<float2*>(out + edge * 2) = ov;
    }
}

extern "C" void kernel_launch(void* const* d_in, const int* in_sizes, int n_in,
                              void* d_out, int out_size, void* d_ws, size_t ws_size,
                              hipStream_t stream) {
    const float* h  = (const float*)d_in[0];
    const float* W1 = (const float*)d_in[1];
    const float* b1 = (const float*)d_in[2];
    const float* W2 = (const float*)d_in[3];
    const float* b2 = (const float*)d_in[4];
    const int* src  = (const int*)d_in[5];
    const int* dst  = (const int*)d_in[6];
    float* out = (float*)d_out;

    const int nwaves = NEDGE / 64;                // 9375
    const int blocks = (nwaves + 3) / 4;          // 2344
    mlp_edge_mfma<<<blocks, 256, 0, stream>>>(h, W1, b1, W2, b2, src, dst, out);
}

// Round 3
// 88.729 us; speedup vs baseline: 2.8016x; 1.1286x over previous
//
#include <hip/hip_runtime.h>
#include <hip/hip_bf16.h>

// Edge MLP via MFMA, bf16 gather table: score = relu((h[src]*h[dst])@W1+b1)@W2+b2
// Round-3 changes vs round-2:
//  - h pre-converted to bf16 (12.8 MB in d_ws) -> gather bytes/loads halved,
//    table fully L3-resident, better per-XCD L2 residency.
//  - W1^T pre-converted to bf16 in d_ws; B-frags read from global (L1-hot,
//    16 KB shared by all waves). No LDS, no __syncthreads, no bank conflicts.
//  - bf16 unpack via exact <<16, product in f32, RNE repack for MFMA A-frag.
// Fallback to the round-2 LDS kernel if ws_size is insufficient.

#define NEDGE 600000
#define NNODES 50000
#define DIN 128
#define DH 64

typedef __attribute__((ext_vector_type(8))) short bf16x8;
typedef __attribute__((ext_vector_type(4))) float f32x4;
typedef __attribute__((ext_vector_type(4))) unsigned int u32x4;

static __device__ __forceinline__ short f2bf(float f) {
    __hip_bfloat16 hb = __float2bfloat16(f);
    return *reinterpret_cast<short*>(&hb);
}
static __device__ __forceinline__ float bflo(unsigned int w) {
    unsigned int u = w << 16;
    return __builtin_bit_cast(float, u);
}
static __device__ __forceinline__ float bfhi(unsigned int w) {
    unsigned int u = w & 0xffff0000u;
    return __builtin_bit_cast(float, u);
}

// ---- prep: h fp32 -> bf16 table (6.4M elems, 4/thread) ----
__global__ __launch_bounds__(256) void cvt_h_kernel(
    const float* __restrict__ h, unsigned short* __restrict__ hbf) {
    int i = (blockIdx.x * 256 + threadIdx.x) * 4;
    f32x4 v = *reinterpret_cast<const f32x4*>(h + i);
    ushort4 o;
    o.x = (unsigned short)f2bf(v[0]);
    o.y = (unsigned short)f2bf(v[1]);
    o.z = (unsigned short)f2bf(v[2]);
    o.w = (unsigned short)f2bf(v[3]);
    *reinterpret_cast<ushort4*>(hbf + i) = o;
}

// ---- prep: W1 [128][64] f32 -> W1t [64][128] bf16 ----
__global__ __launch_bounds__(256) void cvt_w1_kernel(
    const float* __restrict__ W1, unsigned short* __restrict__ w1t) {
    int t = threadIdx.x;
#pragma unroll
    for (int j = 0; j < 8; ++j) {
        int flat = (t + j * 256) * 4;
        f32x4 w = *reinterpret_cast<const f32x4*>(W1 + flat);
        int k = flat >> 6, c = flat & 63;
#pragma unroll
        for (int q = 0; q < 4; ++q)
            w1t[(c + q) * DIN + k] = (unsigned short)f2bf(w[q]);
    }
}

// ---- main: per wave C[64 edges][64 hid] via 64x mfma_f32_16x16x32_bf16 ----
__global__ __launch_bounds__(256) void mlp_edge_mfma_bf(
    const unsigned short* __restrict__ hbf,
    const unsigned short* __restrict__ w1t,
    const float* __restrict__ b1,
    const float* __restrict__ W2,
    const float* __restrict__ b2,
    const int* __restrict__ src,
    const int* __restrict__ dst,
    float* __restrict__ out)
{
    const int tid = threadIdx.x;
    const int l = tid & 63;
    const int lr = l & 15;   // M-row / N-col within 16
    const int g = l >> 4;    // k-group (8 elems each)
    const long long wbase = ((long long)blockIdx.x * 4 + (tid >> 6)) * 64;

    // per-lane gather bases (element offsets into hbf, row = 128 shorts)
    unsigned int sa[4], da[4];
#pragma unroll
    for (int m = 0; m < 4; ++m) {
        long long e = wbase + m * 16 + lr;
        if (e >= NEDGE) e = NEDGE - 1;                  // dummy-wave clamp
        sa[m] = (unsigned int)src[e] * (unsigned)DIN;
        da[m] = (unsigned int)dst[e] * (unsigned)DIN;
    }

    f32x4 acc[4][4];
#pragma unroll
    for (int n = 0; n < 4; ++n) {
        float bv = b1[n * 16 + lr];
#pragma unroll
        for (int m = 0; m < 4; ++m) acc[m][n] = (f32x4){bv, bv, bv, bv};
    }

#pragma unroll
    for (int ks = 0; ks < 4; ++ks) {
        const unsigned int koff = (unsigned)(ks * 32 + g * 8);  // shorts

        // B-frags from global W1t (L1-hot 16 KB, same for all waves)
        bf16x8 B[4];
#pragma unroll
        for (int n = 0; n < 4; ++n)
            B[n] = *reinterpret_cast<const bf16x8*>(w1t + (n * 16 + lr) * DIN + koff);

#pragma unroll
        for (int m = 0; m < 4; ++m) {
            u32x4 s = *reinterpret_cast<const u32x4*>(hbf + sa[m] + koff);
            u32x4 d = *reinterpret_cast<const u32x4*>(hbf + da[m] + koff);
            bf16x8 A;
#pragma unroll
            for (int w = 0; w < 4; ++w) {
                float plo = bflo(s[w]) * bflo(d[w]);
                float phi = bfhi(s[w]) * bfhi(d[w]);
                A[2 * w]     = f2bf(plo);
                A[2 * w + 1] = f2bf(phi);
            }
#pragma unroll
            for (int n = 0; n < 4; ++n)
                acc[m][n] = __builtin_amdgcn_mfma_f32_16x16x32_bf16(A, B[n], acc[m][n], 0, 0, 0);
        }
    }

    // ---- layer 2: relu + [64]->[2], 16-lane butterfly reduce ----
    float w2v[4][2];
#pragma unroll
    for (int n = 0; n < 4; ++n) {
        float2 w = *reinterpret_cast<const float2*>(W2 + (n * 16 + lr) * 2);
        w2v[n][0] = w.x; w2v[n][1] = w.y;
    }
    const float bb0 = b2[0], bb1 = b2[1];

    float o0 = 0.f, o1 = 0.f;
#pragma unroll
    for (int m = 0; m < 4; ++m) {
#pragma unroll
        for (int r = 0; r < 4; ++r) {
            float p0 = 0.f, p1 = 0.f;
#pragma unroll
            for (int n = 0; n < 4; ++n) {
                float v = fmaxf(acc[m][n][r], 0.f);
                p0 = fmaf(v, w2v[n][0], p0);
                p1 = fmaf(v, w2v[n][1], p1);
            }
#pragma unroll
            for (int sh = 1; sh < 16; sh <<= 1) {
                p0 += __shfl_xor(p0, sh, 64);
                p1 += __shfl_xor(p1, sh, 64);
            }
            if (lr == m * 4 + r) { o0 = p0; o1 = p1; }
        }
    }
    long long edge = wbase + ((long long)(lr >> 2) * 16) + g * 4 + (lr & 3);
    if (edge < NEDGE) {
        float2 ov = make_float2(o0 + bb0, o1 + bb1);
        *reinterpret_cast<float2*>(out + edge * 2) = ov;
    }
}

// ================= round-2 fallback (LDS W1^T, fp32 gather) =================
#define STRK 136
__global__ __launch_bounds__(256) void mlp_edge_mfma(
    const float* __restrict__ h, const float* __restrict__ W1,
    const float* __restrict__ b1, const float* __restrict__ W2,
    const float* __restrict__ b2, const int* __restrict__ src,
    const int* __restrict__ dst, float* __restrict__ out)
{
    __shared__ unsigned short w1t[DH * STRK];
    const int tid = threadIdx.x;
#pragma unroll
    for (int j = 0; j < 8; ++j) {
        int flat = (tid + j * 256) * 4;
        f32x4 w = *reinterpret_cast<const f32x4*>(W1 + flat);
        int k = flat >> 6, c = flat & 63;
#pragma unroll
        for (int q = 0; q < 4; ++q)
            w1t[(c + q) * STRK + k] = (unsigned short)f2bf(w[q]);
    }
    __syncthreads();
    const int l = tid & 63, lr = l & 15, g = l >> 4;
    const long long wbase = ((long long)blockIdx.x * 4 + (tid >> 6)) * 64;
    unsigned int sa[4], da[4];
#pragma unroll
    for (int m = 0; m < 4; ++m) {
        long long e = wbase + m * 16 + lr;
        if (e >= NEDGE) e = NEDGE - 1;
        sa[m] = (unsigned int)src[e] * (DIN * 4u);
        da[m] = (unsigned int)dst[e] * (DIN * 4u);
    }
    f32x4 acc[4][4];
#pragma unroll
    for (int n = 0; n < 4; ++n) {
        float bv = b1[n * 16 + lr];
#pragma unroll
        for (int m = 0; m < 4; ++m) acc[m][n] = (f32x4){bv, bv, bv, bv};
    }
    const char* hb8 = (const char*)h;
#pragma unroll
    for (int ks = 0; ks < 4; ++ks) {
        bf16x8 B[4];
#pragma unroll
        for (int n = 0; n < 4; ++n)
            B[n] = *reinterpret_cast<const bf16x8*>(&w1t[(n * 16 + lr) * STRK + ks * 32 + g * 8]);
#pragma unroll
        for (int m = 0; m < 4; ++m) {
            const unsigned int off = (unsigned)(ks * 128 + g * 32);
            f32x4 s0 = *reinterpret_cast<const f32x4*>(hb8 + sa[m] + off);
            f32x4 s1 = *reinterpret_cast<const f32x4*>(hb8 + sa[m] + off + 16);
            f32x4 d0 = *reinterpret_cast<const f32x4*>(hb8 + da[m] + off);
            f32x4 d1 = *reinterpret_cast<const f32x4*>(hb8 + da[m] + off + 16);
            bf16x8 A;
#pragma unroll
            for (int q = 0; q < 4; ++q) {
                A[q]     = f2bf(s0[q] * d0[q]);
                A[q + 4] = f2bf(s1[q] * d1[q]);
            }
#pragma unroll
            for (int n = 0; n < 4; ++n)
                acc[m][n] = __builtin_amdgcn_mfma_f32_16x16x32_bf16(A, B[n], acc[m][n], 0, 0, 0);
        }
    }
    float w2v[4][2];
#pragma unroll
    for (int n = 0; n < 4; ++n) {
        float2 w = *reinterpret_cast<const float2*>(W2 + (n * 16 + lr) * 2);
        w2v[n][0] = w.x; w2v[n][1] = w.y;
    }
    const float bb0 = b2[0], bb1 = b2[1];
    float o0 = 0.f, o1 = 0.f;
#pragma unroll
    for (int m = 0; m < 4; ++m) {
#pragma unroll
        for (int r = 0; r < 4; ++r) {
            float p0 = 0.f, p1 = 0.f;
#pragma unroll
            for (int n = 0; n < 4; ++n) {
                float v = fmaxf(acc[m][n][r], 0.f);
                p0 = fmaf(v, w2v[n][0], p0);
                p1 = fmaf(v, w2v[n][1], p1);
            }
#pragma unroll
            for (int sh = 1; sh < 16; sh <<= 1) {
                p0 += __shfl_xor(p0, sh, 64);
                p1 += __shfl_xor(p1, sh, 64);
            }
            if (lr == m * 4 + r) { o0 = p0; o1 = p1; }
        }
    }
    long long edge = wbase + ((long long)(lr >> 2) * 16) + g * 4 + (lr & 3);
    if (edge < NEDGE) {
        float2 ov = make_float2(o0 + bb0, o1 + bb1);
        *reinterpret_cast<float2*>(out + edge * 2) = ov;
    }
}

extern "C" void kernel_launch(void* const* d_in, const int* in_sizes, int n_in,
                              void* d_out, int out_size, void* d_ws, size_t ws_size,
                              hipStream_t stream) {
    const float* h  = (const float*)d_in[0];
    const float* W1 = (const float*)d_in[1];
    const float* b1 = (const float*)d_in[2];
    const float* W2 = (const float*)d_in[3];
    const float* b2 = (const float*)d_in[4];
    const int* src  = (const int*)d_in[5];
    const int* dst  = (const int*)d_in[6];
    float* out = (float*)d_out;

    const int blocks = (NEDGE / 64 + 3) / 4;  // 2344
    const size_t need = (size_t)NNODES * DIN * 2 + (size_t)DH * DIN * 2;

    if (ws_size >= need) {
        unsigned short* hbf = (unsigned short*)d_ws;
        unsigned short* w1t = hbf + (size_t)NNODES * DIN;   // 12.8 MB offset, 16B-aligned
        cvt_h_kernel<<<(NNODES * DIN) / (256 * 4), 256, 0, stream>>>(h, hbf);
        cvt_w1_kernel<<<1, 256, 0, stream>>>(W1, w1t);
        mlp_edge_mfma_bf<<<blocks, 256, 0, stream>>>(hbf, w1t, b1, W2, b2, src, dst, out);
    } else {
        mlp_edge_mfma<<<blocks, 256, 0, stream>>>(h, W1, b1, W2, b2, src, dst, out);
    }
}